// Round 1
// baseline (8479.581 us; speedup 1.0000x reference)
//
#include <hip/hip_runtime.h>

// Problem constants (B, H, W) from the reference.
#define BB 8
#define HH 1080
#define WW 1920
constexpr int HWc = HH * WW;          // 2,073,600
constexpr int Ntot = BB * HWc;        // 16,588,800

// ---------------------------------------------------------------------------
// Kernel 1: depth-weighted forward splat.
// out  = (B,2,H,W) accumulators for (-fx*w, -fy*w)  [pre-zeroed]
// cnt  = (B,H,W)   accumulator for w                [pre-zeroed]
// Each valid source pixel adds the SAME 3 values to all 4 clamped corners
// (reference semantics: corners that coincide at borders get added twice).
// ---------------------------------------------------------------------------
__global__ __launch_bounds__(256) void splat_k(const float* __restrict__ flow,
                                               const float* __restrict__ depth,
                                               float* __restrict__ out,
                                               float* __restrict__ cnt) {
    int idx = blockIdx.x * 256 + threadIdx.x;
    if (idx >= Ntot) return;
    int b = idx / HWc;
    int p = idx - b * HWc;
    int y = p / WW;
    int x = p - y * WW;

    const size_t fbase = (size_t)b * 2 * HWc;
    float fx = flow[fbase + p];
    float fy = flow[fbase + HWc + p];
    float x2 = (float)x + fx;
    float y2 = (float)y + fy;
    // valid = (x2 in [0, W-1]) && (y2 in [0, H-1]); invalid -> w = 0 -> no-op
    if (!(x2 >= 0.f && x2 <= (float)(WW - 1) && y2 >= 0.f && y2 <= (float)(HH - 1)))
        return;

    float w = depth[(size_t)b * HWc + p];
    int ixL = (int)floorf(x2);
    int iyT = (int)floorf(y2);
    ixL = min(max(ixL, 0), WW - 1);
    iyT = min(max(iyT, 0), HH - 1);
    int ixR = min(ixL + 1, WW - 1);
    int iyB = min(iyT + 1, HH - 1);

    float vx = -fx * w;
    float vy = -fy * w;

    float* o0 = out + fbase;          // channel 0 plane
    float* o1 = o0 + HWc;             // channel 1 plane
    float* cc = cnt + (size_t)b * HWc;

    int c00 = iyT * WW + ixL;
    int c01 = iyT * WW + ixR;
    int c10 = iyB * WW + ixL;
    int c11 = iyB * WW + ixR;

    atomicAdd(o0 + c00, vx); atomicAdd(o1 + c00, vy); atomicAdd(cc + c00, w);
    atomicAdd(o0 + c01, vx); atomicAdd(o1 + c01, vy); atomicAdd(cc + c01, w);
    atomicAdd(o0 + c10, vx); atomicAdd(o1 + c10, vy); atomicAdd(cc + c10, w);
    atomicAdd(o0 + c11, vx); atomicAdd(o1 + c11, vy); atomicAdd(cc + c11, w);
}

// ---------------------------------------------------------------------------
// Kernel 2: in-place average (out /= count where count > 0).
// Holes (count==0) keep the memset 0.0 value, matching acc=0 / denom=1.
// ---------------------------------------------------------------------------
__global__ __launch_bounds__(256) void avg_k(float* __restrict__ out,
                                             const float* __restrict__ cnt) {
    int idx = blockIdx.x * 256 + threadIdx.x;
    if (idx >= Ntot) return;
    float c = cnt[idx];
    if (c > 0.f) {
        int b = idx / HWc;
        int p = idx - b * HWc;
        size_t fbase = (size_t)b * 2 * HWc;
        out[fbase + p]       = out[fbase + p] / c;
        out[fbase + HWc + p] = out[fbase + HWc + p] / c;
    }
}

// ---------------------------------------------------------------------------
// Kernel 3: hole fill. For count==0 pixels, find the nearest filled pixel in
// each of the 4 axis directions; equal-weight average of the found values.
// Reads only filled pixels (stable), writes only holes -> in-place safe.
// Accumulation order matches the reference: left, right, up, down.
// ---------------------------------------------------------------------------
__global__ __launch_bounds__(256) void fill_k(float* __restrict__ out,
                                              const float* __restrict__ cnt) {
    int idx = blockIdx.x * 256 + threadIdx.x;
    if (idx >= Ntot) return;
    if (cnt[idx] > 0.f) return;  // filled pixel: keep averaged value

    int b = idx / HWc;
    int p = idx - b * HWc;
    int y = p / WW;
    int x = p - y * WW;

    const float* cc = cnt + (size_t)b * HWc;
    const float* o0 = out + (size_t)b * 2 * HWc;
    const float* o1 = o0 + HWc;

    float s = 0.f, s0 = 0.f, s1 = 0.f;

    // left
    for (int j = x - 1; j >= 0; --j) {
        int q = y * WW + j;
        if (cc[q] > 0.f) { s += 1.f; s0 += o0[q]; s1 += o1[q]; break; }
    }
    // right
    for (int j = x + 1; j < WW; ++j) {
        int q = y * WW + j;
        if (cc[q] > 0.f) { s += 1.f; s0 += o0[q]; s1 += o1[q]; break; }
    }
    // up
    for (int i = y - 1; i >= 0; --i) {
        int q = i * WW + x;
        if (cc[q] > 0.f) { s += 1.f; s0 += o0[q]; s1 += o1[q]; break; }
    }
    // down
    for (int i = y + 1; i < HH; ++i) {
        int q = i * WW + x;
        if (cc[q] > 0.f) { s += 1.f; s0 += o0[q]; s1 += o1[q]; break; }
    }

    if (s > 0.f) {
        float* w0 = (float*)o0;
        float* w1 = (float*)o1;
        w0[p] = s0 / s;
        w1[p] = s1 / s;
    }
    // else: keep 0.0 (matches reference: hole with no neighbors keeps out=0)
}

extern "C" void kernel_launch(void* const* d_in, const int* in_sizes, int n_in,
                              void* d_out, int out_size, void* d_ws, size_t ws_size,
                              hipStream_t stream) {
    const float* flow  = (const float*)d_in[0];   // (B,2,H,W)
    const float* depth = (const float*)d_in[1];   // (B,1,H,W)
    float* out = (float*)d_out;                   // (B,2,H,W)
    float* cnt = (float*)d_ws;                    // (B,H,W) scratch, 66 MB

    const size_t out_bytes = (size_t)BB * 2 * HWc * sizeof(float);
    const size_t cnt_bytes = (size_t)BB * HWc * sizeof(float);

    // d_out / d_ws are poisoned before every launch: zero them on-stream
    // (graph-capture-safe).
    hipMemsetAsync(d_out, 0, out_bytes, stream);
    hipMemsetAsync(d_ws, 0, cnt_bytes, stream);

    const int threads = 256;
    const int grid = (Ntot + threads - 1) / threads;
    splat_k<<<grid, threads, 0, stream>>>(flow, depth, out, cnt);
    avg_k<<<grid, threads, 0, stream>>>(out, cnt);
    fill_k<<<grid, threads, 0, stream>>>(out, cnt);
}